// Round 1
// baseline (275.134 us; speedup 1.0000x reference)
//
#include <hip/hip_runtime.h>

#define HD 4
#define D 64
#define NHD 256   // HD*D
#define N_IN 256

typedef __attribute__((ext_vector_type(8))) __bf16 bf16x8;
typedef __attribute__((ext_vector_type(4))) __bf16 bf16x4;
typedef __attribute__((ext_vector_type(4))) float f32x4;

constexpr int AROW = 40;   // padded LDS row stride in bf16 (80B = 16B-multiple; 2-way banks = free)

// ---- K1: fused W transpose->bf16 (blocks 0..255) + XCD-privatized in-degree (rest) ----
__global__ __launch_bounds__(256) void pre_kernel(const float* __restrict__ W,
                                                  __bf16* __restrict__ Wt,
                                                  const int* __restrict__ ei,
                                                  int* __restrict__ deg8, int Nn, int E) {
  const int b = blockIdx.x;
  if (b < N_IN) {
    const int k = b, n = threadIdx.x;
    Wt[n * N_IN + k] = (__bf16)W[k * NHD + n];
  } else {
    const int e = (b - N_IN) * 256 + threadIdx.x;
    const int c = b & 7;   // plane = XCD under round-robin dispatch -> XCD-local atomics
    if (e < E) atomicAdd(&deg8[c * Nn + ei[E + e]], 1);
  }
}

// ---- K2: fused scan pass 1 (blocks 0..NB-1) + MFMA GEMM 128x256 tile (rest) ----
__global__ __launch_bounds__(512) void gemm_scan_kernel(
    const float* __restrict__ A, const __bf16* __restrict__ Wt,
    const float* __restrict__ a_src, const float* __restrict__ a_dst,
    __bf16* __restrict__ hp16, float* __restrict__ s_out, float* __restrict__ t_out,
    int M, const int* __restrict__ deg8, int* __restrict__ partial,
    int* __restrict__ blocksum, int NB, int MT) {
  __shared__ __bf16 As[128 * AROW];
  __shared__ __bf16 Bs[256 * AROW];
  __shared__ int ws4[4];
  const int tid = threadIdx.x;

  if ((int)blockIdx.x < NB) {
    // ---------------- scan1: per-1024-node chunk scan of total degrees ----------------
    const int lane = tid & 63, wv = tid >> 6;
    const int base = blockIdx.x * 1024 + tid * 4;
    int v[4], sum = 0, incl = 0;
    if (tid < 256) {
#pragma unroll
      for (int j = 0; j < 4; ++j) {
        int n = base + j;
        int s = 0;
        if (n < M) {
#pragma unroll
          for (int c = 0; c < 8; ++c) s += deg8[c * M + n];
        }
        v[j] = s;
      }
      sum = v[0] + v[1] + v[2] + v[3];
      incl = sum;
#pragma unroll
      for (int off = 1; off < 64; off <<= 1) {
        int y = __shfl_up(incl, off);
        if (lane >= off) incl += y;
      }
      if (lane == 63) ws4[wv] = incl;
    }
    __syncthreads();
    if (tid < 256) {
      int wbase = 0;
#pragma unroll
      for (int w = 0; w < 4; ++w)
        if (w < wv) wbase += ws4[w];
      int excl = wbase + incl - sum;
      if (base + 0 < M) partial[base + 0] = excl;
      if (base + 1 < M) partial[base + 1] = excl + v[0];
      if (base + 2 < M) partial[base + 2] = excl + v[0] + v[1];
      if (base + 3 < M) partial[base + 3] = excl + v[0] + v[1] + v[2];
      if (tid == 255) blocksum[blockIdx.x] = wbase + incl;
    }
    return;
  }

  // ---------------- gemm: hp16 = bf16(h @ W), 128x256 tile, 8 waves, fused s/t ----------------
  const int g = blockIdx.x - NB;         // row tile index, 0..MT-1
  const int lane = tid & 63, wv = tid >> 6;
  const int wr = wv >> 2, wc = wv & 3;   // wave grid 2x4 over 128x256
  const int c15 = lane & 15, quad = lane >> 4;
  const int m0 = g * 128;

  f32x4 acc[4][4];
#pragma unroll
  for (int i = 0; i < 4; ++i)
#pragma unroll
    for (int j = 0; j < 4; ++j) acc[i][j] = (f32x4){0.f, 0.f, 0.f, 0.f};

  // A staging: 128 rows x 32 k per chunk; 4 threads/row, 8 floats each
  const int am = tid >> 2, aks = (tid & 3) * 8;
  const int gr = m0 + am;
  const bool arow_ok = (gr < M);
  const float* Arow = &A[(size_t)gr * N_IN];
  // B staging: 256 rows x 32 k per chunk; 2 threads/row, 16 bf16 each
  const int bm = tid >> 1, bks = (tid & 1) * 16;
  const __bf16* Brow = &Wt[(size_t)bm * N_IN];

  for (int kc = 0; kc < 8; ++kc) {
    const int k0 = kc * 32;
    float4 f0, f1;
    if (arow_ok) {
      f0 = *(const float4*)&Arow[k0 + aks + 0];
      f1 = *(const float4*)&Arow[k0 + aks + 4];
    } else {
      f0 = f1 = make_float4(0.f, 0.f, 0.f, 0.f);
    }
    bf16x8 b0 = *(const bf16x8*)&Brow[k0 + bks];
    bf16x8 b1 = *(const bf16x8*)&Brow[k0 + bks + 8];

    __syncthreads();
    bf16x8 a0;
    a0[0] = (__bf16)f0.x; a0[1] = (__bf16)f0.y; a0[2] = (__bf16)f0.z; a0[3] = (__bf16)f0.w;
    a0[4] = (__bf16)f1.x; a0[5] = (__bf16)f1.y; a0[6] = (__bf16)f1.z; a0[7] = (__bf16)f1.w;
    *(bf16x8*)&As[am * AROW + aks] = a0;
    *(bf16x8*)&Bs[bm * AROW + bks] = b0;
    *(bf16x8*)&Bs[bm * AROW + bks + 8] = b1;
    __syncthreads();

    bf16x8 af[4], bf_[4];
#pragma unroll
    for (int i = 0; i < 4; ++i) {
      af[i]  = *(bf16x8*)&As[(wr * 64 + i * 16 + c15) * AROW + quad * 8];
      bf_[i] = *(bf16x8*)&Bs[(wc * 64 + i * 16 + c15) * AROW + quad * 8];
    }
#pragma unroll
    for (int mi = 0; mi < 4; ++mi)
#pragma unroll
      for (int ni = 0; ni < 4; ++ni)
        acc[mi][ni] = __builtin_amdgcn_mfma_f32_16x16x32_bf16(af[mi], bf_[ni], acc[mi][ni], 0, 0, 0);
  }

  const int head = wc;
  float av[4], ad[4];
#pragma unroll
  for (int ni = 0; ni < 4; ++ni) {
    av[ni] = a_src[head * D + ni * 16 + c15];
    ad[ni] = a_dst[head * D + ni * 16 + c15];
  }
  const int row0w = m0 + wr * 64;
#pragma unroll
  for (int mi = 0; mi < 4; ++mi) {
#pragma unroll
    for (int j = 0; j < 4; ++j) {
      float ps = acc[mi][0][j] * av[0] + acc[mi][1][j] * av[1] +
                 acc[mi][2][j] * av[2] + acc[mi][3][j] * av[3];
      float pt = acc[mi][0][j] * ad[0] + acc[mi][1][j] * ad[1] +
                 acc[mi][2][j] * ad[2] + acc[mi][3][j] * ad[3];
#pragma unroll
      for (int m = 1; m < 16; m <<= 1) {
        ps += __shfl_xor(ps, m);
        pt += __shfl_xor(pt, m);
      }
      const int row = row0w + mi * 16 + quad * 4 + j;
      if (c15 == 0 && row < M) {
        s_out[row * HD + head] = ps;
        t_out[row * HD + head] = pt;
      }
    }
#pragma unroll
    for (int ni = 0; ni < 4; ++ni) {
#pragma unroll
      for (int j = 0; j < 4; ++j) {
        const int row = row0w + mi * 16 + quad * 4 + j;
        const int col = wc * 64 + ni * 16 + c15;
        if (row < M) hp16[(size_t)row * NHD + col] = (__bf16)acc[mi][ni][j];
      }
    }
  }
}

// ---- K3: scan 2+3: block-offset scan + per-node row_ptr + per-(node,plane) cursors ----
__global__ __launch_bounds__(256) void scan23_kernel(const int* __restrict__ partial,
                                                     const int* __restrict__ blocksum,
                                                     const int* __restrict__ deg8,
                                                     int* __restrict__ row_ptr,
                                                     int* __restrict__ cursor8, int n, int NB) {
  __shared__ int s_off;
  const int tid = threadIdx.x;
  if (tid < 64) {
    int v = (tid < NB) ? blocksum[tid] : 0;
    int incl = v;
#pragma unroll
    for (int off = 1; off < 64; off <<= 1) {
      int y = __shfl_up(incl, off);
      if (tid >= off) incl += y;
    }
    int prev = __shfl_up(incl, 1);
    int excl = (tid == 0) ? 0 : prev;
    if (tid == (int)blockIdx.x) s_off = excl;
    if (blockIdx.x == 0 && tid == NB - 1) row_ptr[n] = incl;   // grand total
  }
  __syncthreads();
  const int off = s_off;
  const int base = blockIdx.x * 1024 + tid * 4;
#pragma unroll
  for (int j = 0; j < 4; ++j) {
    const int node = base + j;
    if (node < n) {
      int rp = partial[node] + off;
      row_ptr[node] = rp;
      int run = rp;
#pragma unroll
      for (int c = 0; c < 8; ++c) {
        cursor8[c * n + node] = run;
        run += deg8[c * n + node];
      }
    }
  }
}

// ---- K4: per-edge scatter into CSR, XCD-privatized cursors ----
__global__ void scatter_kernel(const int* __restrict__ ei, int* __restrict__ cursor8,
                               int* __restrict__ csr_src, int Nn, int E) {
  int e = blockIdx.x * blockDim.x + threadIdx.x;
  if (e >= E) return;
  const int c = blockIdx.x & 7;   // same plane choice as pre_kernel's degree pass
  int sn = ei[e], dn = ei[E + e];
  int pos = atomicAdd(&cursor8[c * Nn + dn], 1);
  csr_src[pos] = sn;
}

// ---- K5: per-dst aggregation: 1 wave/node, 4 dims/lane, 8 gathers in flight ----
__global__ __launch_bounds__(256) void aggregate_kernel(
    const int* __restrict__ row_ptr, const int* __restrict__ csr_src,
    const float* __restrict__ s, const float* __restrict__ t,
    const __bf16* __restrict__ hp16, float* __restrict__ out, int N) {
  const int wave = threadIdx.x >> 6;
  const int lane = threadIdx.x & 63;
  const int node = blockIdx.x * 4 + wave;
  if (node >= N) return;
  const int h = lane >> 4;
  const int d0 = lane * 4;
  const int beg = row_ptr[node], end = row_ptr[node + 1];
  const float tn = t[node * HD + h];
  float num0 = 0.f, num1 = 0.f, num2 = 0.f, num3 = 0.f, den = 0.f;
  int i = beg;
  // 8-wide main loop: 8 row-gathers + 8 s-gathers in flight
  for (; i + 8 <= end; i += 8) {
    int sn[8];
#pragma unroll
    for (int u = 0; u < 8; ++u) sn[u] = csr_src[i + u];
    bf16x4 v[8];
#pragma unroll
    for (int u = 0; u < 8; ++u) v[u] = *(const bf16x4*)&hp16[(size_t)sn[u] * NHD + d0];
    float lg[8];
#pragma unroll
    for (int u = 0; u < 8; ++u) lg[u] = s[sn[u] * HD + h] + tn;
#pragma unroll
    for (int u = 0; u < 8; ++u) {
      lg[u] = fmaxf(lg[u], 0.2f * lg[u]);
      lg[u] = __expf(lg[u]);
    }
#pragma unroll
    for (int u = 0; u < 8; ++u) {
      den  += lg[u];
      num0 += lg[u] * (float)v[u][0];
      num1 += lg[u] * (float)v[u][1];
      num2 += lg[u] * (float)v[u][2];
      num3 += lg[u] * (float)v[u][3];
    }
  }
  // 4-wide
  for (; i + 4 <= end; i += 4) {
    int sn0 = csr_src[i], sn1 = csr_src[i + 1], sn2 = csr_src[i + 2], sn3 = csr_src[i + 3];
    bf16x4 v0 = *(const bf16x4*)&hp16[(size_t)sn0 * NHD + d0];
    bf16x4 v1 = *(const bf16x4*)&hp16[(size_t)sn1 * NHD + d0];
    bf16x4 v2 = *(const bf16x4*)&hp16[(size_t)sn2 * NHD + d0];
    bf16x4 v3 = *(const bf16x4*)&hp16[(size_t)sn3 * NHD + d0];
    float lg0 = s[sn0 * HD + h] + tn;
    float lg1 = s[sn1 * HD + h] + tn;
    float lg2 = s[sn2 * HD + h] + tn;
    float lg3 = s[sn3 * HD + h] + tn;
    lg0 = fmaxf(lg0, 0.2f * lg0);
    lg1 = fmaxf(lg1, 0.2f * lg1);
    lg2 = fmaxf(lg2, 0.2f * lg2);
    lg3 = fmaxf(lg3, 0.2f * lg3);
    float ex0 = __expf(lg0), ex1 = __expf(lg1), ex2 = __expf(lg2), ex3 = __expf(lg3);
    den += (ex0 + ex1) + (ex2 + ex3);
    num0 += ex0 * (float)v0[0] + ex1 * (float)v1[0] + ex2 * (float)v2[0] + ex3 * (float)v3[0];
    num1 += ex0 * (float)v0[1] + ex1 * (float)v1[1] + ex2 * (float)v2[1] + ex3 * (float)v3[1];
    num2 += ex0 * (float)v0[2] + ex1 * (float)v1[2] + ex2 * (float)v2[2] + ex3 * (float)v3[2];
    num3 += ex0 * (float)v0[3] + ex1 * (float)v1[3] + ex2 * (float)v2[3] + ex3 * (float)v3[3];
  }
  // scalar tail
  for (; i < end; ++i) {
    int sn0 = csr_src[i];
    bf16x4 v0 = *(const bf16x4*)&hp16[(size_t)sn0 * NHD + d0];
    float lg0 = s[sn0 * HD + h] + tn;
    lg0 = fmaxf(lg0, 0.2f * lg0);
    float ex0 = __expf(lg0);
    den += ex0;
    num0 += ex0 * (float)v0[0];
    num1 += ex0 * (float)v0[1];
    num2 += ex0 * (float)v0[2];
    num3 += ex0 * (float)v0[3];
  }
  const float inv = 1.0f / (den + 1e-16f);
  float4 o = make_float4(num0 * inv, num1 * inv, num2 * inv, num3 * inv);
  *(float4*)&out[(size_t)node * NHD + d0] = o;
}

extern "C" void kernel_launch(void* const* d_in, const int* in_sizes, int n_in,
                              void* d_out, int out_size, void* d_ws, size_t ws_size,
                              hipStream_t stream) {
  const float* h_ptr  = (const float*)d_in[0];
  const int*   ei     = (const int*)d_in[1];
  const float* W      = (const float*)d_in[2];
  const float* a_src  = (const float*)d_in[3];
  const float* a_dst  = (const float*)d_in[4];
  float* out = (float*)d_out;

  const int N = in_sizes[0] / N_IN;     // 50000
  const int E = in_sizes[1] / 2;        // 800000
  const int NB = (N + 1023) / 1024;     // 49 scan chunks
  const int MT = (N + 127) / 128;       // 391 gemm m-tiles

  auto align256 = [](size_t x) { return (x + 255) & ~size_t(255); };
  char* base = (char*)d_ws;
  size_t off = 0;
  __bf16* hp16 = (__bf16*)(base + off);  off += align256((size_t)N * NHD * 2);
  __bf16* Wt   = (__bf16*)(base + off);  off += align256((size_t)N_IN * NHD * 2);
  float* s       = (float*)(base + off); off += align256((size_t)N * HD * 4);
  float* t       = (float*)(base + off); off += align256((size_t)N * HD * 4);
  int*   deg8    = (int*)(base + off);   off += align256((size_t)N * 8 * 4);
  int*   cursor8 = (int*)(base + off);   off += align256((size_t)N * 8 * 4);
  int*   partial = (int*)(base + off);   off += align256((size_t)N * 4);
  int*   blocksum= (int*)(base + off);   off += align256((size_t)NB * 4);
  int*   row_ptr = (int*)(base + off);   off += align256((size_t)(N + 1) * 4);
  int*   csr_src = (int*)(base + off);   off += align256((size_t)E * 4);

  // 0. zero privatized degree planes
  hipMemsetAsync(deg8, 0, (size_t)N * 8 * 4, stream);
  // 1. fused W-transpose + privatized degree
  pre_kernel<<<N_IN + (E + 255) / 256, 256, 0, stream>>>(W, Wt, ei, deg8, N, E);
  // 2. fused scan1 + MFMA GEMM (128x256 tile, A read once)
  gemm_scan_kernel<<<NB + MT, 512, 0, stream>>>(h_ptr, Wt, a_src, a_dst,
                                                hp16, s, t, N, deg8, partial,
                                                blocksum, NB, MT);
  // 3. scan2+3 -> row_ptr + privatized cursors
  scan23_kernel<<<NB, 256, 0, stream>>>(partial, blocksum, deg8, row_ptr, cursor8, N, NB);
  // 4. per-edge scatter (privatized cursors)
  scatter_kernel<<<(E + 255) / 256, 256, 0, stream>>>(ei, cursor8, csr_src, N, E);
  // 5. per-dst aggregation
  aggregate_kernel<<<(N + 3) / 4, 256, 0, stream>>>(row_ptr, csr_src, s, t, hp16, out, N);
}

// Round 2
// 273.793 us; speedup vs baseline: 1.0049x; 1.0049x over previous
//
#include <hip/hip_runtime.h>

#define HD 4
#define D 64
#define NHD 256   // HD*D
#define N_IN 256

typedef __attribute__((ext_vector_type(8))) __bf16 bf16x8;
typedef __attribute__((ext_vector_type(4))) __bf16 bf16x4;
typedef __attribute__((ext_vector_type(4))) float f32x4;

constexpr int AROW = 40;   // padded LDS row stride in bf16 (80B = 16B-multiple; 2-way banks = free)

// ---- K1: fused W transpose->bf16 (blocks 0..255) + XCD-privatized in-degree (rest) ----
__global__ __launch_bounds__(256) void pre_kernel(const float* __restrict__ W,
                                                  __bf16* __restrict__ Wt,
                                                  const int* __restrict__ ei,
                                                  int* __restrict__ deg8, int Nn, int E) {
  const int b = blockIdx.x;
  if (b < N_IN) {
    const int k = b, n = threadIdx.x;
    Wt[n * N_IN + k] = (__bf16)W[k * NHD + n];
  } else {
    const int e = (b - N_IN) * 256 + threadIdx.x;
    const int c = b & 7;   // plane = XCD under round-robin dispatch -> XCD-local atomics
    if (e < E) atomicAdd(&deg8[c * Nn + ei[E + e]], 1);
  }
}

// ---- K2: fused scan pass 1 (blocks 0..NB-1) + MFMA GEMM 128x256 tile (rest) ----
__global__ __launch_bounds__(512) void gemm_scan_kernel(
    const float* __restrict__ A, const __bf16* __restrict__ Wt,
    const float* __restrict__ a_src, const float* __restrict__ a_dst,
    __bf16* __restrict__ hp16, float* __restrict__ s_out, float* __restrict__ t_out,
    int M, const int* __restrict__ deg8, int* __restrict__ partial,
    int* __restrict__ blocksum, int NB, int MT) {
  __shared__ __bf16 As[128 * AROW];
  __shared__ __bf16 Bs[256 * AROW];
  __shared__ int ws4[4];
  const int tid = threadIdx.x;

  if ((int)blockIdx.x < NB) {
    // ---------------- scan1: per-1024-node chunk scan of total degrees ----------------
    const int lane = tid & 63, wv = tid >> 6;
    const int base = blockIdx.x * 1024 + tid * 4;
    int v[4], sum = 0, incl = 0;
    if (tid < 256) {
#pragma unroll
      for (int j = 0; j < 4; ++j) {
        int n = base + j;
        int s = 0;
        if (n < M) {
#pragma unroll
          for (int c = 0; c < 8; ++c) s += deg8[c * M + n];
        }
        v[j] = s;
      }
      sum = v[0] + v[1] + v[2] + v[3];
      incl = sum;
#pragma unroll
      for (int off = 1; off < 64; off <<= 1) {
        int y = __shfl_up(incl, off);
        if (lane >= off) incl += y;
      }
      if (lane == 63) ws4[wv] = incl;
    }
    __syncthreads();
    if (tid < 256) {
      int wbase = 0;
#pragma unroll
      for (int w = 0; w < 4; ++w)
        if (w < wv) wbase += ws4[w];
      int excl = wbase + incl - sum;
      if (base + 0 < M) partial[base + 0] = excl;
      if (base + 1 < M) partial[base + 1] = excl + v[0];
      if (base + 2 < M) partial[base + 2] = excl + v[0] + v[1];
      if (base + 3 < M) partial[base + 3] = excl + v[0] + v[1] + v[2];
      if (tid == 255) blocksum[blockIdx.x] = wbase + incl;
    }
    return;
  }

  // ---------------- gemm: hp16 = bf16(h @ W), 128x256 tile, 8 waves, fused s/t ----------------
  const int g = blockIdx.x - NB;         // row tile index, 0..MT-1
  const int lane = tid & 63, wv = tid >> 6;
  const int wr = wv >> 2, wc = wv & 3;   // wave grid 2x4 over 128x256
  const int c15 = lane & 15, quad = lane >> 4;
  const int m0 = g * 128;

  f32x4 acc[4][4];
#pragma unroll
  for (int i = 0; i < 4; ++i)
#pragma unroll
    for (int j = 0; j < 4; ++j) acc[i][j] = (f32x4){0.f, 0.f, 0.f, 0.f};

  // A staging: 128 rows x 32 k per chunk; 4 threads/row, 8 floats each
  const int am = tid >> 2, aks = (tid & 3) * 8;
  const int gr = m0 + am;
  const bool arow_ok = (gr < M);
  const float* Arow = &A[(size_t)gr * N_IN];
  // B staging: 256 rows x 32 k per chunk; 2 threads/row, 16 bf16 each
  const int bm = tid >> 1, bks = (tid & 1) * 16;
  const __bf16* Brow = &Wt[(size_t)bm * N_IN];

  for (int kc = 0; kc < 8; ++kc) {
    const int k0 = kc * 32;
    float4 f0, f1;
    if (arow_ok) {
      f0 = *(const float4*)&Arow[k0 + aks + 0];
      f1 = *(const float4*)&Arow[k0 + aks + 4];
    } else {
      f0 = f1 = make_float4(0.f, 0.f, 0.f, 0.f);
    }
    bf16x8 b0 = *(const bf16x8*)&Brow[k0 + bks];
    bf16x8 b1 = *(const bf16x8*)&Brow[k0 + bks + 8];

    __syncthreads();
    bf16x8 a0;
    a0[0] = (__bf16)f0.x; a0[1] = (__bf16)f0.y; a0[2] = (__bf16)f0.z; a0[3] = (__bf16)f0.w;
    a0[4] = (__bf16)f1.x; a0[5] = (__bf16)f1.y; a0[6] = (__bf16)f1.z; a0[7] = (__bf16)f1.w;
    *(bf16x8*)&As[am * AROW + aks] = a0;
    *(bf16x8*)&Bs[bm * AROW + bks] = b0;
    *(bf16x8*)&Bs[bm * AROW + bks + 8] = b1;
    __syncthreads();

    bf16x8 af[4], bf_[4];
#pragma unroll
    for (int i = 0; i < 4; ++i) {
      af[i]  = *(bf16x8*)&As[(wr * 64 + i * 16 + c15) * AROW + quad * 8];
      bf_[i] = *(bf16x8*)&Bs[(wc * 64 + i * 16 + c15) * AROW + quad * 8];
    }
#pragma unroll
    for (int mi = 0; mi < 4; ++mi)
#pragma unroll
      for (int ni = 0; ni < 4; ++ni)
        acc[mi][ni] = __builtin_amdgcn_mfma_f32_16x16x32_bf16(af[mi], bf_[ni], acc[mi][ni], 0, 0, 0);
  }

  const int head = wc;
  float av[4], ad[4];
#pragma unroll
  for (int ni = 0; ni < 4; ++ni) {
    av[ni] = a_src[head * D + ni * 16 + c15];
    ad[ni] = a_dst[head * D + ni * 16 + c15];
  }
  const int row0w = m0 + wr * 64;
#pragma unroll
  for (int mi = 0; mi < 4; ++mi) {
#pragma unroll
    for (int j = 0; j < 4; ++j) {
      float ps = acc[mi][0][j] * av[0] + acc[mi][1][j] * av[1] +
                 acc[mi][2][j] * av[2] + acc[mi][3][j] * av[3];
      float pt = acc[mi][0][j] * ad[0] + acc[mi][1][j] * ad[1] +
                 acc[mi][2][j] * ad[2] + acc[mi][3][j] * ad[3];
#pragma unroll
      for (int m = 1; m < 16; m <<= 1) {
        ps += __shfl_xor(ps, m);
        pt += __shfl_xor(pt, m);
      }
      const int row = row0w + mi * 16 + quad * 4 + j;
      if (c15 == 0 && row < M) {
        s_out[row * HD + head] = ps;
        t_out[row * HD + head] = pt;
      }
    }
#pragma unroll
    for (int ni = 0; ni < 4; ++ni) {
#pragma unroll
      for (int j = 0; j < 4; ++j) {
        const int row = row0w + mi * 16 + quad * 4 + j;
        const int col = wc * 64 + ni * 16 + c15;
        if (row < M) hp16[(size_t)row * NHD + col] = (__bf16)acc[mi][ni][j];
      }
    }
  }
}

// ---- K3: scan 2+3: block-offset scan + per-node row_ptr + per-(node,plane) cursors ----
__global__ __launch_bounds__(256) void scan23_kernel(const int* __restrict__ partial,
                                                     const int* __restrict__ blocksum,
                                                     const int* __restrict__ deg8,
                                                     int* __restrict__ row_ptr,
                                                     int* __restrict__ cursor8, int n, int NB) {
  __shared__ int s_off;
  const int tid = threadIdx.x;
  if (tid < 64) {
    int v = (tid < NB) ? blocksum[tid] : 0;
    int incl = v;
#pragma unroll
    for (int off = 1; off < 64; off <<= 1) {
      int y = __shfl_up(incl, off);
      if (tid >= off) incl += y;
    }
    int prev = __shfl_up(incl, 1);
    int excl = (tid == 0) ? 0 : prev;
    if (tid == (int)blockIdx.x) s_off = excl;
    if (blockIdx.x == 0 && tid == NB - 1) row_ptr[n] = incl;   // grand total
  }
  __syncthreads();
  const int off = s_off;
  const int base = blockIdx.x * 1024 + tid * 4;
#pragma unroll
  for (int j = 0; j < 4; ++j) {
    const int node = base + j;
    if (node < n) {
      int rp = partial[node] + off;
      row_ptr[node] = rp;
      int run = rp;
#pragma unroll
      for (int c = 0; c < 8; ++c) {
        cursor8[c * n + node] = run;
        run += deg8[c * n + node];
      }
    }
  }
}

// ---- K4: per-edge scatter into CSR, XCD-privatized cursors ----
__global__ void scatter_kernel(const int* __restrict__ ei, int* __restrict__ cursor8,
                               int* __restrict__ csr_src, int Nn, int E) {
  int e = blockIdx.x * blockDim.x + threadIdx.x;
  if (e >= E) return;
  const int c = blockIdx.x & 7;   // same plane choice as pre_kernel's degree pass
  int sn = ei[e], dn = ei[E + e];
  int pos = atomicAdd(&cursor8[c * Nn + dn], 1);
  csr_src[pos] = sn;
}

// ---- K5: per-dst aggregation: 1 wave/node, scalar (SGPR) addressing for all gathers ----
__global__ __launch_bounds__(256) void aggregate_kernel(
    const int* __restrict__ row_ptr, const int* __restrict__ csr_src,
    const float* __restrict__ s, const float* __restrict__ t,
    const __bf16* __restrict__ hp16, float* __restrict__ out, int N) {
  const int wave = threadIdx.x >> 6;
  const int lane = threadIdx.x & 63;
  const int node = blockIdx.x * 4 + wave;
  if (node >= N) return;
  const int h = lane >> 4;
  const int d0 = lane * 4;
  // wave-uniform loop bounds -> SGPRs (scalar loop control, SALU address math)
  const int beg = __builtin_amdgcn_readfirstlane(row_ptr[node]);
  const int end = __builtin_amdgcn_readfirstlane(row_ptr[node + 1]);
  const float tn = t[node * HD + h];
  float num0 = 0.f, num1 = 0.f, num2 = 0.f, num3 = 0.f, den = 0.f;
  int i = beg;
  // 8-wide main loop: ONE coalesced 32B index load, indices distributed via readlane;
  // all gather bases are scalar (saddr form) -> address math on the SALU pipe.
  for (; i + 8 <= end; i += 8) {
    const int my = csr_src[i + (lane & 7)];
    int sn[8];
#pragma unroll
    for (int u = 0; u < 8; ++u) sn[u] = __builtin_amdgcn_readlane(my, u);
    bf16x4 v[8];
#pragma unroll
    for (int u = 0; u < 8; ++u) v[u] = *(const bf16x4*)&hp16[(size_t)sn[u] * NHD + d0];
    float lg[8];
#pragma unroll
    for (int u = 0; u < 8; ++u) lg[u] = s[sn[u] * HD + h] + tn;
#pragma unroll
    for (int u = 0; u < 8; ++u) {
      lg[u] = fmaxf(lg[u], 0.2f * lg[u]);
      lg[u] = __expf(lg[u]);
    }
#pragma unroll
    for (int u = 0; u < 8; ++u) {
      den  += lg[u];
      num0 += lg[u] * (float)v[u][0];
      num1 += lg[u] * (float)v[u][1];
      num2 += lg[u] * (float)v[u][2];
      num3 += lg[u] * (float)v[u][3];
    }
  }
  // 4-wide
  for (; i + 4 <= end; i += 4) {
    const int my = csr_src[i + (lane & 3)];
    int sn[4];
#pragma unroll
    for (int u = 0; u < 4; ++u) sn[u] = __builtin_amdgcn_readlane(my, u);
    bf16x4 v[4];
#pragma unroll
    for (int u = 0; u < 4; ++u) v[u] = *(const bf16x4*)&hp16[(size_t)sn[u] * NHD + d0];
    float lg[4];
#pragma unroll
    for (int u = 0; u < 4; ++u) lg[u] = s[sn[u] * HD + h] + tn;
#pragma unroll
    for (int u = 0; u < 4; ++u) {
      lg[u] = fmaxf(lg[u], 0.2f * lg[u]);
      lg[u] = __expf(lg[u]);
    }
#pragma unroll
    for (int u = 0; u < 4; ++u) {
      den  += lg[u];
      num0 += lg[u] * (float)v[u][0];
      num1 += lg[u] * (float)v[u][1];
      num2 += lg[u] * (float)v[u][2];
      num3 += lg[u] * (float)v[u][3];
    }
  }
  // scalar tail
  for (; i < end; ++i) {
    const int sn0 = __builtin_amdgcn_readfirstlane(csr_src[i]);
    bf16x4 v0 = *(const bf16x4*)&hp16[(size_t)sn0 * NHD + d0];
    float lg0 = s[sn0 * HD + h] + tn;
    lg0 = fmaxf(lg0, 0.2f * lg0);
    float ex0 = __expf(lg0);
    den += ex0;
    num0 += ex0 * (float)v0[0];
    num1 += ex0 * (float)v0[1];
    num2 += ex0 * (float)v0[2];
    num3 += ex0 * (float)v0[3];
  }
  const float inv = 1.0f / (den + 1e-16f);
  float4 o = make_float4(num0 * inv, num1 * inv, num2 * inv, num3 * inv);
  *(float4*)&out[(size_t)node * NHD + d0] = o;
}

extern "C" void kernel_launch(void* const* d_in, const int* in_sizes, int n_in,
                              void* d_out, int out_size, void* d_ws, size_t ws_size,
                              hipStream_t stream) {
  const float* h_ptr  = (const float*)d_in[0];
  const int*   ei     = (const int*)d_in[1];
  const float* W      = (const float*)d_in[2];
  const float* a_src  = (const float*)d_in[3];
  const float* a_dst  = (const float*)d_in[4];
  float* out = (float*)d_out;

  const int N = in_sizes[0] / N_IN;     // 50000
  const int E = in_sizes[1] / 2;        // 800000
  const int NB = (N + 1023) / 1024;     // 49 scan chunks
  const int MT = (N + 127) / 128;       // 391 gemm m-tiles

  auto align256 = [](size_t x) { return (x + 255) & ~size_t(255); };
  char* base = (char*)d_ws;
  size_t off = 0;
  __bf16* hp16 = (__bf16*)(base + off);  off += align256((size_t)N * NHD * 2);
  __bf16* Wt   = (__bf16*)(base + off);  off += align256((size_t)N_IN * NHD * 2);
  float* s       = (float*)(base + off); off += align256((size_t)N * HD * 4);
  float* t       = (float*)(base + off); off += align256((size_t)N * HD * 4);
  int*   deg8    = (int*)(base + off);   off += align256((size_t)N * 8 * 4);
  int*   cursor8 = (int*)(base + off);   off += align256((size_t)N * 8 * 4);
  int*   partial = (int*)(base + off);   off += align256((size_t)N * 4);
  int*   blocksum= (int*)(base + off);   off += align256((size_t)NB * 4);
  int*   row_ptr = (int*)(base + off);   off += align256((size_t)(N + 1) * 4);
  int*   csr_src = (int*)(base + off);   off += align256((size_t)E * 4);

  // 0. zero privatized degree planes
  hipMemsetAsync(deg8, 0, (size_t)N * 8 * 4, stream);
  // 1. fused W-transpose + privatized degree
  pre_kernel<<<N_IN + (E + 255) / 256, 256, 0, stream>>>(W, Wt, ei, deg8, N, E);
  // 2. fused scan1 + MFMA GEMM (128x256 tile, A read once)
  gemm_scan_kernel<<<NB + MT, 512, 0, stream>>>(h_ptr, Wt, a_src, a_dst,
                                                hp16, s, t, N, deg8, partial,
                                                blocksum, NB, MT);
  // 3. scan2+3 -> row_ptr + privatized cursors
  scan23_kernel<<<NB, 256, 0, stream>>>(partial, blocksum, deg8, row_ptr, cursor8, N, NB);
  // 4. per-edge scatter (privatized cursors)
  scatter_kernel<<<(E + 255) / 256, 256, 0, stream>>>(ei, cursor8, csr_src, N, E);
  // 5. per-dst aggregation
  aggregate_kernel<<<(N + 3) / 4, 256, 0, stream>>>(row_ptr, csr_src, s, t, hp16, out, N);
}

// Round 3
// 273.650 us; speedup vs baseline: 1.0054x; 1.0005x over previous
//
#include <hip/hip_runtime.h>

#define HD 4
#define D 64
#define NHD 256   // HD*D
#define N_IN 256

typedef __attribute__((ext_vector_type(8))) __bf16 bf16x8;
typedef __attribute__((ext_vector_type(4))) __bf16 bf16x4;
typedef __attribute__((ext_vector_type(4))) float f32x4;

constexpr int AROW = 40;   // padded LDS row stride in bf16 (80B = 16B-multiple; 2-way banks = free)

// ---- K1: fused W transpose->bf16 (blocks 0..255) + XCD-privatized in-degree (rest) ----
__global__ __launch_bounds__(256) void pre_kernel(const float* __restrict__ W,
                                                  __bf16* __restrict__ Wt,
                                                  const int* __restrict__ ei,
                                                  int* __restrict__ deg8, int Nn, int E) {
  const int b = blockIdx.x;
  if (b < N_IN) {
    const int k = b, n = threadIdx.x;
    Wt[n * N_IN + k] = (__bf16)W[k * NHD + n];
  } else {
    const int e = (b - N_IN) * 256 + threadIdx.x;
    const int c = b & 7;   // plane = XCD under round-robin dispatch -> XCD-local atomics
    if (e < E) atomicAdd(&deg8[c * Nn + ei[E + e]], 1);
  }
}

// ---- K2: fused scan pass 1 (blocks 0..NB-1) + MFMA GEMM 128x256 tile (rest) ----
__global__ __launch_bounds__(512) void gemm_scan_kernel(
    const float* __restrict__ A, const __bf16* __restrict__ Wt,
    const float* __restrict__ a_src, const float* __restrict__ a_dst,
    __bf16* __restrict__ hp16, float* __restrict__ s_out, float* __restrict__ t_out,
    int M, const int* __restrict__ deg8, int* __restrict__ partial,
    int* __restrict__ blocksum, int NB, int MT) {
  __shared__ __bf16 As[128 * AROW];
  __shared__ __bf16 Bs[256 * AROW];
  __shared__ int ws4[4];
  const int tid = threadIdx.x;

  if ((int)blockIdx.x < NB) {
    // ---------------- scan1: per-1024-node chunk scan of total degrees ----------------
    const int lane = tid & 63, wv = tid >> 6;
    const int base = blockIdx.x * 1024 + tid * 4;
    int v[4], sum = 0, incl = 0;
    if (tid < 256) {
#pragma unroll
      for (int j = 0; j < 4; ++j) {
        int n = base + j;
        int s = 0;
        if (n < M) {
#pragma unroll
          for (int c = 0; c < 8; ++c) s += deg8[c * M + n];
        }
        v[j] = s;
      }
      sum = v[0] + v[1] + v[2] + v[3];
      incl = sum;
#pragma unroll
      for (int off = 1; off < 64; off <<= 1) {
        int y = __shfl_up(incl, off);
        if (lane >= off) incl += y;
      }
      if (lane == 63) ws4[wv] = incl;
    }
    __syncthreads();
    if (tid < 256) {
      int wbase = 0;
#pragma unroll
      for (int w = 0; w < 4; ++w)
        if (w < wv) wbase += ws4[w];
      int excl = wbase + incl - sum;
      if (base + 0 < M) partial[base + 0] = excl;
      if (base + 1 < M) partial[base + 1] = excl + v[0];
      if (base + 2 < M) partial[base + 2] = excl + v[0] + v[1];
      if (base + 3 < M) partial[base + 3] = excl + v[0] + v[1] + v[2];
      if (tid == 255) blocksum[blockIdx.x] = wbase + incl;
    }
    return;
  }

  // ---------------- gemm: hp16 = bf16(h @ W), 128x256 tile, 8 waves, fused s/t ----------------
  const int g = blockIdx.x - NB;         // row tile index, 0..MT-1
  const int lane = tid & 63, wv = tid >> 6;
  const int wr = wv >> 2, wc = wv & 3;   // wave grid 2x4 over 128x256
  const int c15 = lane & 15, quad = lane >> 4;
  const int m0 = g * 128;

  f32x4 acc[4][4];
#pragma unroll
  for (int i = 0; i < 4; ++i)
#pragma unroll
    for (int j = 0; j < 4; ++j) acc[i][j] = (f32x4){0.f, 0.f, 0.f, 0.f};

  // A staging: 128 rows x 32 k per chunk; 4 threads/row, 8 floats each
  const int am = tid >> 2, aks = (tid & 3) * 8;
  const int gr = m0 + am;
  const bool arow_ok = (gr < M);
  const float* Arow = &A[(size_t)gr * N_IN];
  // B staging: 256 rows x 32 k per chunk; 2 threads/row, 16 bf16 each
  const int bm = tid >> 1, bks = (tid & 1) * 16;
  const __bf16* Brow = &Wt[(size_t)bm * N_IN];

  for (int kc = 0; kc < 8; ++kc) {
    const int k0 = kc * 32;
    float4 f0, f1;
    if (arow_ok) {
      f0 = *(const float4*)&Arow[k0 + aks + 0];
      f1 = *(const float4*)&Arow[k0 + aks + 4];
    } else {
      f0 = f1 = make_float4(0.f, 0.f, 0.f, 0.f);
    }
    bf16x8 b0 = *(const bf16x8*)&Brow[k0 + bks];
    bf16x8 b1 = *(const bf16x8*)&Brow[k0 + bks + 8];

    __syncthreads();
    bf16x8 a0;
    a0[0] = (__bf16)f0.x; a0[1] = (__bf16)f0.y; a0[2] = (__bf16)f0.z; a0[3] = (__bf16)f0.w;
    a0[4] = (__bf16)f1.x; a0[5] = (__bf16)f1.y; a0[6] = (__bf16)f1.z; a0[7] = (__bf16)f1.w;
    *(bf16x8*)&As[am * AROW + aks] = a0;
    *(bf16x8*)&Bs[bm * AROW + bks] = b0;
    *(bf16x8*)&Bs[bm * AROW + bks + 8] = b1;
    __syncthreads();

    bf16x8 af[4], bf_[4];
#pragma unroll
    for (int i = 0; i < 4; ++i) {
      af[i]  = *(bf16x8*)&As[(wr * 64 + i * 16 + c15) * AROW + quad * 8];
      bf_[i] = *(bf16x8*)&Bs[(wc * 64 + i * 16 + c15) * AROW + quad * 8];
    }
#pragma unroll
    for (int mi = 0; mi < 4; ++mi)
#pragma unroll
      for (int ni = 0; ni < 4; ++ni)
        acc[mi][ni] = __builtin_amdgcn_mfma_f32_16x16x32_bf16(af[mi], bf_[ni], acc[mi][ni], 0, 0, 0);
  }

  const int head = wc;
  float av[4], ad[4];
#pragma unroll
  for (int ni = 0; ni < 4; ++ni) {
    av[ni] = a_src[head * D + ni * 16 + c15];
    ad[ni] = a_dst[head * D + ni * 16 + c15];
  }
  const int row0w = m0 + wr * 64;
#pragma unroll
  for (int mi = 0; mi < 4; ++mi) {
#pragma unroll
    for (int j = 0; j < 4; ++j) {
      float ps = acc[mi][0][j] * av[0] + acc[mi][1][j] * av[1] +
                 acc[mi][2][j] * av[2] + acc[mi][3][j] * av[3];
      float pt = acc[mi][0][j] * ad[0] + acc[mi][1][j] * ad[1] +
                 acc[mi][2][j] * ad[2] + acc[mi][3][j] * ad[3];
#pragma unroll
      for (int m = 1; m < 16; m <<= 1) {
        ps += __shfl_xor(ps, m);
        pt += __shfl_xor(pt, m);
      }
      const int row = row0w + mi * 16 + quad * 4 + j;
      if (c15 == 0 && row < M) {
        s_out[row * HD + head] = ps;
        t_out[row * HD + head] = pt;
      }
    }
#pragma unroll
    for (int ni = 0; ni < 4; ++ni) {
#pragma unroll
      for (int j = 0; j < 4; ++j) {
        const int row = row0w + mi * 16 + quad * 4 + j;
        const int col = wc * 64 + ni * 16 + c15;
        if (row < M) hp16[(size_t)row * NHD + col] = (__bf16)acc[mi][ni][j];
      }
    }
  }
}

// ---- K3: scan 2+3: block-offset scan + per-node row_ptr + per-(node,plane) cursors ----
__global__ __launch_bounds__(256) void scan23_kernel(const int* __restrict__ partial,
                                                     const int* __restrict__ blocksum,
                                                     const int* __restrict__ deg8,
                                                     int* __restrict__ row_ptr,
                                                     int* __restrict__ cursor8, int n, int NB) {
  __shared__ int s_off;
  const int tid = threadIdx.x;
  if (tid < 64) {
    int v = (tid < NB) ? blocksum[tid] : 0;
    int incl = v;
#pragma unroll
    for (int off = 1; off < 64; off <<= 1) {
      int y = __shfl_up(incl, off);
      if (tid >= off) incl += y;
    }
    int prev = __shfl_up(incl, 1);
    int excl = (tid == 0) ? 0 : prev;
    if (tid == (int)blockIdx.x) s_off = excl;
    if (blockIdx.x == 0 && tid == NB - 1) row_ptr[n] = incl;   // grand total
  }
  __syncthreads();
  const int off = s_off;
  const int base = blockIdx.x * 1024 + tid * 4;
#pragma unroll
  for (int j = 0; j < 4; ++j) {
    const int node = base + j;
    if (node < n) {
      int rp = partial[node] + off;
      row_ptr[node] = rp;
      int run = rp;
#pragma unroll
      for (int c = 0; c < 8; ++c) {
        cursor8[c * n + node] = run;
        run += deg8[c * n + node];
      }
    }
  }
}

// ---- K4: per-edge scatter into CSR, XCD-privatized cursors ----
__global__ __launch_bounds__(256) void scatter_kernel(const int* __restrict__ ei, int* __restrict__ cursor8,
                                                      int* __restrict__ csr_src, int Nn, int E) {
  int e = blockIdx.x * blockDim.x + threadIdx.x;
  if (e >= E) return;
  const int c = blockIdx.x & 7;   // same plane choice as pre_kernel's degree pass
  int sn = ei[e], dn = ei[E + e];
  int pos = atomicAdd(&cursor8[c * Nn + dn], 1);
  csr_src[pos] = sn;
}

// ---- K5: per-dst aggregation: 1 wave/node, lane-parallel alpha (16 edges x 4 heads),
//          per-edge 512B row gather with scalar base addressing ----
__global__ __launch_bounds__(256) void aggregate_kernel(
    const int* __restrict__ row_ptr, const int* __restrict__ csr_src,
    const float* __restrict__ s, const float* __restrict__ t,
    const __bf16* __restrict__ hp16, float* __restrict__ out, int N) {
  const int wave = threadIdx.x >> 6;
  const int lane = threadIdx.x & 63;
  const int node = blockIdx.x * 4 + wave;
  if (node >= N) return;
  const int h = lane >> 4;        // head for BOTH this lane's dims and its alpha slot
  const int j = lane & 15;        // edge slot within a 16-batch
  const int d0 = lane * 4;        // 4 dims of head h (d0/64 == h)
  const int exbase = lane & 48;   // shfl source group base: h*16
  const int beg = row_ptr[node], end = row_ptr[node + 1];
  const float tn = t[node * HD + h];
  float num0 = 0.f, num1 = 0.f, num2 = 0.f, num3 = 0.f, den = 0.f;

  int i = beg;
  if (i < end) {
    // prefetch first index batch (coalesced 64B over 16 lanes; tail clamped)
    int rem0 = end - i;
    int sn_cur = csr_src[i + (j < rem0 ? j : rem0 - 1)];
    while (i < end) {
      const int rem = end - i;
      const int cnt = rem < 16 ? rem : 16;
      const int inext = i + 16;
      // double-buffered index load: issued a full batch ahead so its vmcnt wait
      // never drains the in-flight row gathers below
      int sn_next = 0;
      if (inext < end) {
        int rem2 = end - inext;
        sn_next = csr_src[inext + (j < rem2 ? j : rem2 - 1)];
      }
      // ---- phase 1: lane-parallel alpha: 16 edges x 4 heads in one shot ----
      float lg = s[sn_cur * HD + h] + tn;
      lg = fmaxf(lg, 0.2f * lg);
      float ex = (j < rem) ? __expf(lg) : 0.f;
      den += ex;
      // ---- phase 2: per-edge coalesced 512B row gather + FMA ----
      if (cnt == 16) {
#pragma unroll
        for (int u = 0; u < 16; ++u) {
          const int snu = __builtin_amdgcn_readlane(sn_cur, u);   // SGPR -> SALU addressing
          const float exu = __shfl(ex, exbase + u);               // alpha(edge u, head h)
          bf16x4 v = *(const bf16x4*)&hp16[(unsigned)snu * (unsigned)NHD + (unsigned)d0];
          num0 += exu * (float)v[0];
          num1 += exu * (float)v[1];
          num2 += exu * (float)v[2];
          num3 += exu * (float)v[3];
        }
      } else {
        for (int u = 0; u < cnt; ++u) {
          const int snu = __builtin_amdgcn_readlane(sn_cur, u);
          const float exu = __shfl(ex, exbase + u);
          bf16x4 v = *(const bf16x4*)&hp16[(unsigned)snu * (unsigned)NHD + (unsigned)d0];
          num0 += exu * (float)v[0];
          num1 += exu * (float)v[1];
          num2 += exu * (float)v[2];
          num3 += exu * (float)v[3];
        }
      }
      sn_cur = sn_next;
      i = inext;
    }
  }
  // reduce den over the 16 edge slots within each head group (lanes h*16..h*16+15)
#pragma unroll
  for (int m = 1; m < 16; m <<= 1) den += __shfl_xor(den, m);
  const float inv = 1.0f / (den + 1e-16f);
  float4 o = make_float4(num0 * inv, num1 * inv, num2 * inv, num3 * inv);
  *(float4*)&out[(size_t)node * NHD + d0] = o;
}

extern "C" void kernel_launch(void* const* d_in, const int* in_sizes, int n_in,
                              void* d_out, int out_size, void* d_ws, size_t ws_size,
                              hipStream_t stream) {
  const float* h_ptr  = (const float*)d_in[0];
  const int*   ei     = (const int*)d_in[1];
  const float* W      = (const float*)d_in[2];
  const float* a_src  = (const float*)d_in[3];
  const float* a_dst  = (const float*)d_in[4];
  float* out = (float*)d_out;

  const int N = in_sizes[0] / N_IN;     // 50000
  const int E = in_sizes[1] / 2;        // 800000
  const int NB = (N + 1023) / 1024;     // 49 scan chunks
  const int MT = (N + 127) / 128;       // 391 gemm m-tiles

  auto align256 = [](size_t x) { return (x + 255) & ~size_t(255); };
  char* base = (char*)d_ws;
  size_t off = 0;
  __bf16* hp16 = (__bf16*)(base + off);  off += align256((size_t)N * NHD * 2);
  __bf16* Wt   = (__bf16*)(base + off);  off += align256((size_t)N_IN * NHD * 2);
  float* s       = (float*)(base + off); off += align256((size_t)N * HD * 4);
  float* t       = (float*)(base + off); off += align256((size_t)N * HD * 4);
  int*   deg8    = (int*)(base + off);   off += align256((size_t)N * 8 * 4);
  int*   cursor8 = (int*)(base + off);   off += align256((size_t)N * 8 * 4);
  int*   partial = (int*)(base + off);   off += align256((size_t)N * 4);
  int*   blocksum= (int*)(base + off);   off += align256((size_t)NB * 4);
  int*   row_ptr = (int*)(base + off);   off += align256((size_t)(N + 1) * 4);
  int*   csr_src = (int*)(base + off);   off += align256((size_t)E * 4);

  // 0. zero privatized degree planes
  hipMemsetAsync(deg8, 0, (size_t)N * 8 * 4, stream);
  // 1. fused W-transpose + privatized degree
  pre_kernel<<<N_IN + (E + 255) / 256, 256, 0, stream>>>(W, Wt, ei, deg8, N, E);
  // 2. fused scan1 + MFMA GEMM (128x256 tile, A read once)
  gemm_scan_kernel<<<NB + MT, 512, 0, stream>>>(h_ptr, Wt, a_src, a_dst,
                                                hp16, s, t, N, deg8, partial,
                                                blocksum, NB, MT);
  // 3. scan2+3 -> row_ptr + privatized cursors
  scan23_kernel<<<NB, 256, 0, stream>>>(partial, blocksum, deg8, row_ptr, cursor8, N, NB);
  // 4. per-edge scatter (privatized cursors)
  scatter_kernel<<<(E + 255) / 256, 256, 0, stream>>>(ei, cursor8, csr_src, N, E);
  // 5. per-dst aggregation
  aggregate_kernel<<<(N + 3) / 4, 256, 0, stream>>>(row_ptr, csr_src, s, t, hp16, out, N);
}